// Round 15
// baseline (193.633 us; speedup 1.0000x reference)
//
#include <hip/hip_runtime.h>
#include <hip/hip_bf16.h>
#include <hip/hip_cooperative_groups.h>

namespace cg = cooperative_groups;

typedef __attribute__((ext_vector_type(4)))  float f32x4;
typedef __attribute__((ext_vector_type(16))) float f32x16;
typedef __attribute__((ext_vector_type(8)))  short bf16x8;
typedef __attribute__((ext_vector_type(4)))  unsigned int u32x4;

__device__ __forceinline__ unsigned int pk2bf(float x, float y){
    union { __hip_bfloat162 h; unsigned int u; } cv;
    float2 f; f.x = x; f.y = y;
    cv.h = __float22bfloat162_rn(f);                 // v_cvt_pk_bf16_f32
    return cv.u;
}
__device__ __forceinline__ bf16x8 pk8(const f32x4 lo, const f32x4 hi){
    u32x4 u;
    u[0] = pk2bf(lo[0], lo[1]); u[1] = pk2bf(lo[2], lo[3]);
    u[2] = pk2bf(hi[0], hi[1]); u[3] = pk2bf(hi[2], hi[3]);
    return __builtin_bit_cast(bf16x8, u);
}

// ---------------------------------------------------------------- single cooperative kernel
// 256 blocks x 512 thr, LDS 147,456 B -> exactly 1 block/CU co-resident (cooperative-safe).
// Phase 0: stage W2 -> LDS in 32x32-tile order.
// Phase 1 (by global wave id, 2048 waves):
//   [0,1536)    Bws(f32)[32-row x 32-col tile] = doc @ W1b   (32x32x16 MFMA)
//   [1536,1664) dense[32 docs x 32 q] = doc @ query^T        (32x32x16 MFMA)
//   [1664,1676) Aq(f32)[32 q x 32 cols] = query @ W1a + b1
//   [1676,1804) sparse passthrough copy (1024 floats/wave)
// grid.sync()
// Phase 2: round-11 main (best measured: 1 dcol/wave x 6 n-tiles, 24 ksteps, 1-deep global
// prefetch, no LDS prefetch) + packed pk8 converts + all-f32 operands (no bf16 unpacks).
// MFMA layouts: A m=lane&31,k=(lane>>5)*8+j; B n=lane&31 same k;
// C/D col=lane&31, row=(reg&3)+8*(reg>>2)+4*(lane>>5)  [m74/m101-verified].
__global__ __launch_bounds__(512, 2)
void fused_kernel(const float* __restrict__ query, const float* __restrict__ doc,
                  const float* __restrict__ sparse, const float* __restrict__ W1,
                  const float* __restrict__ b1, const float* __restrict__ W2,
                  const float* __restrict__ b2, const float* __restrict__ W3,
                  const float* __restrict__ b3,
                  float* __restrict__ out_final, float* __restrict__ out_dense,
                  float* __restrict__ out_sparse,
                  float* __restrict__ Bws, float* __restrict__ Aq){
    __shared__ short lw[73728];                      // 147,456 B
    const int tid = threadIdx.x;
    const int lane = tid & 63, w = tid >> 6;
    const int m = lane & 31, q2 = lane >> 5;
    const int kbase = q2*8;

    // ---- phase 0: stage W2 -> LDS (chunk c=(s*6+t2)*64+lane_c; reg j = W2[k][n],
    // n=t2*32+(lane_c&31), k=s*16+((lane_c>>5)&1)*8+j)
    #pragma unroll
    for (int i=0;i<18;i++){
        int c = tid + i*512;
        int lane_c = c & 63, st = c >> 6;
        int s = st/6, t2 = st%6;
        int n = t2*32 + (lane_c&31), kb = s*16 + ((lane_c>>5)&1)*8;
        u32x4 vu;
        #pragma unroll
        for (int p=0;p<4;p++)
            vu[p] = pk2bf(W2[(kb+2*p)*192 + n], W2[(kb+2*p+1)*192 + n]);
        *(bf16x8*)(lw + c*8) = __builtin_bit_cast(bf16x8, vu);
    }

    // ---- phase 1: by global wave id
    const int gw = blockIdx.x*8 + w;
    if (gw < 1536){
        // Bws 32x32 tile: rows r0.., cols c0..
        const int r0 = (gw/12)*32, c0 = (gw%12)*32;
        const float* w1b = W1 + 384*384;
        f32x16 acc;
        #pragma unroll
        for (int r=0;r<16;r++) acc[r] = 0.0f;
        #pragma unroll 1
        for (int s=0;s<24;s++){
            const int k0 = s*16 + kbase;
            const float* dp = doc + (r0+m)*384 + k0;
            const bf16x8 af = pk8(*(const f32x4*)dp, *(const f32x4*)(dp+4));
            const float* wk = w1b + k0*384 + c0 + m;
            u32x4 bu;
            #pragma unroll
            for (int p=0;p<4;p++)
                bu[p] = pk2bf(wk[(2*p)*384], wk[(2*p+1)*384]);
            const bf16x8 bf_ = __builtin_bit_cast(bf16x8, bu);
            acc = __builtin_amdgcn_mfma_f32_32x32x16_bf16(af, bf_, acc, 0, 0, 0);
        }
        #pragma unroll
        for (int r=0;r<16;r++){
            const int row = (r&3) + 8*(r>>2) + 4*q2;
            Bws[(r0+row)*384 + c0 + m] = acc[r];
        }
    } else if (gw < 1664){
        // dense 32x32: docs d0.., all 32 q.  A=doc rows, B=query rows (contiguous 32B loads)
        const int d0 = (gw-1536)*32;
        f32x16 acc;
        #pragma unroll
        for (int r=0;r<16;r++) acc[r] = 0.0f;
        #pragma unroll 1
        for (int s=0;s<24;s++){
            const int k0 = s*16 + kbase;
            const float* dp = doc + (d0+m)*384 + k0;
            const float* qp = query + m*384 + k0;
            const bf16x8 af = pk8(*(const f32x4*)dp, *(const f32x4*)(dp+4));
            const bf16x8 bf_ = pk8(*(const f32x4*)qp, *(const f32x4*)(qp+4));
            acc = __builtin_amdgcn_mfma_f32_32x32x16_bf16(af, bf_, acc, 0, 0, 0);
        }
        #pragma unroll
        for (int r=0;r<16;r++){
            const int row = (r&3) + 8*(r>>2) + 4*q2;     // doc offset
            out_dense[m*4096 + d0 + row] = acc[r];       // col m = query index
        }
    } else if (gw < 1676){
        // Aq 32x32: all 32 q rows, cols c0..
        const int c0 = (gw-1664)*32;
        f32x16 acc;
        #pragma unroll
        for (int r=0;r<16;r++) acc[r] = 0.0f;
        #pragma unroll 1
        for (int s=0;s<24;s++){
            const int k0 = s*16 + kbase;
            const float* qp = query + m*384 + k0;
            const bf16x8 af = pk8(*(const f32x4*)qp, *(const f32x4*)(qp+4));
            const float* wk = W1 + k0*384 + c0 + m;
            u32x4 bu;
            #pragma unroll
            for (int p=0;p<4;p++)
                bu[p] = pk2bf(wk[(2*p)*384], wk[(2*p+1)*384]);
            const bf16x8 bf_ = __builtin_bit_cast(bf16x8, bu);
            acc = __builtin_amdgcn_mfma_f32_32x32x16_bf16(af, bf_, acc, 0, 0, 0);
        }
        const float b1v = b1[c0 + m];
        #pragma unroll
        for (int r=0;r<16;r++){
            const int row = (r&3) + 8*(r>>2) + 4*q2;     // q row
            Aq[row*384 + c0 + m] = acc[r] + b1v;
        }
    } else if (gw < 1804){
        // sparse copy: 1024 floats per wave
        const int base = (gw-1676)*256;                  // in f32x4 units
        #pragma unroll
        for (int i=0;i<4;i++){
            int v = base + i*64 + lane;
            *(f32x4*)(out_sparse + v*4) = *(const f32x4*)(sparse + v*4);
        }
    }

    cg::this_grid().sync();

    // ---- phase 2: fused MLP main (round-11 structure, f32 operands, pk8 converts)
    const float b3v = b3[0];
    const float* w1c = W1 + 768*384;
    const float* w1d = W1 + 769*384;

    #pragma unroll 1
    for (int t4=0; t4<2; t4++){
        const int dcol = blockIdx.x*16 + t4*8 + w;       // doc column, < 4096
        const float dsv = out_dense[m*4096 + dcol];
        const float ssv = sparse[m*4096 + dcol];

        f32x16 acc[6];
        #pragma unroll
        for (int t=0;t<6;t++)
            #pragma unroll
            for (int r=0;r<16;r++) acc[t][r] = 0.0f;

        // 1-deep global prefetch
        f32x4 a0_c = *(const f32x4*)(Aq + m*384 + kbase);
        f32x4 a1_c = *(const f32x4*)(Aq + m*384 + kbase + 4);
        f32x4 b0_c = *(const f32x4*)(Bws + dcol*384 + kbase);
        f32x4 b1_c = *(const f32x4*)(Bws + dcol*384 + kbase + 4);

        #pragma unroll 1
        for (int s=0;s<24;s++){
            const int k0 = s*16 + kbase;
            const int kn = (s < 23) ? (k0 + 16) : kbase; // dummy wrap on last iter
            const f32x4 a0_n = *(const f32x4*)(Aq + m*384 + kn);
            const f32x4 a1_n = *(const f32x4*)(Aq + m*384 + kn + 4);
            const f32x4 b0_n = *(const f32x4*)(Bws + dcol*384 + kn);
            const f32x4 b1_n = *(const f32x4*)(Bws + dcol*384 + kn + 4);
            const f32x4 wc0 = *(const f32x4*)(w1c + k0);
            const f32x4 wc1 = *(const f32x4*)(w1c + k0 + 4);
            const f32x4 wd0 = *(const f32x4*)(w1d + k0);
            const f32x4 wd1 = *(const f32x4*)(w1d + k0 + 4);
            f32x4 h0, h1;
            #pragma unroll
            for (int j=0;j<4;j++){
                h0[j] = fmaxf(a0_c[j] + b0_c[j] + dsv*wc0[j] + ssv*wd0[j], 0.0f);
                h1[j] = fmaxf(a1_c[j] + b1_c[j] + dsv*wc1[j] + ssv*wd1[j], 0.0f);
            }
            const bf16x8 fr = pk8(h0, h1);
            #pragma unroll
            for (int t=0;t<6;t++){
                const bf16x8 bfr = *(const bf16x8*)(lw + ((s*6 + t)*64 + lane)*8);
                acc[t] = __builtin_amdgcn_mfma_f32_32x32x16_bf16(fr, bfr, acc[t], 0, 0, 0);
            }
            a0_c = a0_n; a1_c = a1_n; b0_c = b0_n; b1_c = b1_n;
        }

        // layer 3: lane covers n = t*32+m
        float p[16];
        #pragma unroll
        for (int r=0;r<16;r++) p[r] = 0.0f;
        #pragma unroll
        for (int t=0;t<6;t++){
            const int n = t*32 + m;
            const float b2v = b2[n];
            const float w3v = W3[n];
            #pragma unroll
            for (int r=0;r<16;r++)
                p[r] += fmaxf(acc[t][r] + b2v, 0.0f) * w3v;
        }
        #pragma unroll
        for (int mask=1; mask<32; mask<<=1){
            #pragma unroll
            for (int r=0;r<16;r++) p[r] += __shfl_xor(p[r], mask);
        }
        float myp = p[0];
        #pragma unroll
        for (int r=1;r<16;r++) myp = (m==r) ? p[r] : myp;
        if (m < 16){
            const int row = (m&3) + 8*(m>>2) + 4*q2;
            float logit = myp + b3v;
            float wgt = 1.0f/(1.0f + __expf(-logit));
            float dd = out_dense[row*4096 + dcol];
            float ss = sparse[row*4096 + dcol];
            out_final[row*4096 + dcol] = wgt*dd + (1.0f - wgt)*ss;
        }
    }
}

// ---------------------------------------------------------------- launch
extern "C" void kernel_launch(void* const* d_in, const int* in_sizes, int n_in,
                              void* d_out, int out_size, void* d_ws, size_t ws_size,
                              hipStream_t stream){
    const float* query  = (const float*)d_in[0];
    const float* doc    = (const float*)d_in[1];
    const float* sparse = (const float*)d_in[2];
    const float* W1     = (const float*)d_in[3];
    const float* b1     = (const float*)d_in[4];
    const float* W2     = (const float*)d_in[5];
    const float* b2     = (const float*)d_in[6];
    const float* W3     = (const float*)d_in[7];
    const float* b3     = (const float*)d_in[8];

    float* out_final  = (float*)d_out;                 // [32,4096]
    float* out_dense  = (float*)d_out + 131072;        // [32,4096]
    float* out_sparse = (float*)d_out + 262144;        // [32,4096]

    // workspace layout (16B-aligned), total 6,340,608 B
    float* Bws = (float*)d_ws;                                    // 6,291,456 B  (f32 [4096][384])
    float* Aq  = (float*)((char*)d_ws + 6291456);                 //    49,152 B  (f32 [32][384])

    void* args[] = { (void*)&query, (void*)&doc, (void*)&sparse, (void*)&W1, (void*)&b1,
                     (void*)&W2, (void*)&b2, (void*)&W3, (void*)&b3,
                     (void*)&out_final, (void*)&out_dense, (void*)&out_sparse,
                     (void*)&Bws, (void*)&Aq };
    hipLaunchCooperativeKernel((const void*)fused_kernel, dim3(256), dim3(512),
                               args, 0, stream);
}

// Round 16
// 145.666 us; speedup vs baseline: 1.3293x; 1.3293x over previous
//
#include <hip/hip_runtime.h>
#include <hip/hip_bf16.h>

typedef __attribute__((ext_vector_type(4)))  float f32x4;
typedef __attribute__((ext_vector_type(16))) float f32x16;
typedef __attribute__((ext_vector_type(8)))  short bf16x8;
typedef __attribute__((ext_vector_type(4)))  unsigned int u32x4;

__device__ __forceinline__ unsigned int pk2bf(float x, float y){
    union { __hip_bfloat162 h; unsigned int u; } cv;
    float2 f; f.x = x; f.y = y;
    cv.h = __float22bfloat162_rn(f);                 // v_cvt_pk_bf16_f32
    return cv.u;
}
__device__ __forceinline__ bf16x8 pk8(const f32x4 lo, const f32x4 hi){
    u32x4 u;
    u[0] = pk2bf(lo[0], lo[1]); u[1] = pk2bf(lo[2], lo[3]);
    u[2] = pk2bf(hi[0], hi[1]); u[3] = pk2bf(hi[2], hi[3]);
    return __builtin_bit_cast(bf16x8, u);
}

// ---------------------------------------------------------------- pre
// blocks 0..63   : dense scores via MFMA (64 docs x 32 q per block; wave = 16 docs)
// blocks 64..319 : Bws(f32)[16 doc rows] = doc @ W1b
// blocks 320,321 : Aq(f32)[16 q rows]    = query @ W1a + b1
// blocks 322..353: sparse passthrough copy (f32x4 flat)
__global__ __launch_bounds__(256)
void pre_kernel(const float* __restrict__ query, const float* __restrict__ doc,
                const float* __restrict__ sparse, const float* __restrict__ W1,
                const float* __restrict__ b1,
                float* __restrict__ out_dense, float* __restrict__ out_sparse,
                float* __restrict__ Bws, float* __restrict__ Aq){
    const int b = blockIdx.x, tid = threadIdx.x;
    const int w = tid >> 6, lane = tid & 63;
    const int cl = lane & 15, quad = lane >> 4;

    if (b < 64){
        // dense = doc-tile @ query^T : A=doc rows (m), B=query rows (n), 12 ksteps of 32
        const int dbase = b*64 + w*16;
        f32x4 acc0 = (f32x4){0.f,0.f,0.f,0.f};
        f32x4 acc1 = (f32x4){0.f,0.f,0.f,0.f};
        #pragma unroll 1
        for (int s=0;s<12;s++){
            const int k0 = s*32 + quad*8;
            const float* dp = doc + (dbase + cl)*384 + k0;
            const bf16x8 af = pk8(*(const f32x4*)dp, *(const f32x4*)(dp+4));
            const float* q0p = query + cl*384 + k0;
            const float* q1p = query + (16+cl)*384 + k0;
            const bf16x8 bf0 = pk8(*(const f32x4*)q0p, *(const f32x4*)(q0p+4));
            const bf16x8 bf1 = pk8(*(const f32x4*)q1p, *(const f32x4*)(q1p+4));
            acc0 = __builtin_amdgcn_mfma_f32_16x16x32_bf16(af, bf0, acc0, 0, 0, 0);
            acc1 = __builtin_amdgcn_mfma_f32_16x16x32_bf16(af, bf1, acc1, 0, 0, 0);
        }
        // D: col=lane&15 -> q within tile, row=quad*4+r -> doc
        #pragma unroll
        for (int r=0;r<4;r++){
            const int d = dbase + quad*4 + r;
            out_dense[cl*4096 + d]      = acc0[r];
            out_dense[(16+cl)*4096 + d] = acc1[r];
        }
    } else if (b < 322){
        const int bb = b - 64;
        const float* src; const float* wrow; int r0; bool isA;
        if (bb < 256){ r0 = bb*16;       src = doc;   wrow = W1 + 384*384; isA = false; }
        else         { r0 = (bb-256)*16; src = query; wrow = W1;           isA = true;  }

        f32x4 acc[6];
        #pragma unroll
        for (int t=0;t<6;t++) acc[t] = (f32x4){0.f,0.f,0.f,0.f};

        #pragma unroll 1
        for (int s=0;s<12;s++){
            const float* ap = src + (r0+cl)*384 + s*32 + quad*8;
            const bf16x8 af = pk8(*(const f32x4*)ap, *(const f32x4*)(ap+4));
            const float* wk = wrow + (s*32 + quad*8)*384;
            #pragma unroll
            for (int tt=0;tt<6;tt++){
                const int col = (w*6+tt)*16 + cl;
                u32x4 bu;
                #pragma unroll
                for (int p=0;p<4;p++)
                    bu[p] = pk2bf(wk[(2*p)*384 + col], wk[(2*p+1)*384 + col]);
                const bf16x8 bf_ = __builtin_bit_cast(bf16x8, bu);
                acc[tt] = __builtin_amdgcn_mfma_f32_16x16x32_bf16(af, bf_, acc[tt], 0, 0, 0);
            }
        }
        float* out = isA ? Aq : Bws;
        #pragma unroll
        for (int tt=0;tt<6;tt++){
            const int col = (w*6+tt)*16 + cl;
            const float b1v = isA ? b1[col] : 0.0f;
            #pragma unroll
            for (int r=0;r<4;r++)
                out[(r0 + quad*4 + r)*384 + col] = acc[tt][r] + b1v;
        }
    } else {
        // flat f32x4 copy: 32768 vec4 total, 1024 per block, 4 per thread
        const int base = (b - 322)*1024;
        #pragma unroll
        for (int i=0;i<4;i++){
            int v = base + i*256 + tid;
            *(f32x4*)(out_sparse + v*4) = *(const f32x4*)(sparse + v*4);
        }
    }
}

// ---------------------------------------------------------------- main fused MLP kernel
// ROUND-11 CHAMPION STRUCTURE (47.6us measured) + micro-deltas only:
// 256 blocks x 512 thr = 8 waves, 1 block/CU. One wave = one doc column x 32 q x 192 N via
// mfma_f32_32x32x16_bf16, 6 n-tiles, 24 ksteps, 1-deep GLOBAL prefetch only (LDS prefetch
// regressed in r13; 2-dcol split regressed in r14; coop fusion regressed in r15).
// Deltas vs r11: packed pk8 converts; Bws/wc/wd kept f32 (kills 24 bf2f unpacks/kstep);
// b2r/w3r hoisted out of the t4 loop. acc = 96 AGPR, arch regs ~100 < 128 budget.
// A-frag: m=lane&31, k=(lane>>5)*8+j.  B-frag: n=lane&31, same k.
// C/D: col=lane&31, row=(reg&3)+8*(reg>>2)+4*(lane>>5)  [m74/m101-verified].
__global__ __launch_bounds__(512, 2)
void main_kernel(const float* __restrict__ Aq, const float* __restrict__ Bws,
                 const float* __restrict__ W1,
                 const float* __restrict__ b2, const float* __restrict__ W3,
                 const float* __restrict__ b3, const float* __restrict__ sparse,
                 const float* __restrict__ W2, const float* __restrict__ dense_in,
                 float* __restrict__ out_final){
    __shared__ short lw[73728];                      // 147,456 B
    const int tid = threadIdx.x;
    // stage W2 -> LDS in 32x32-tile order: chunk c=(s*6+t2)*64+lane_c, reg j = W2[k][n],
    // n = t2*32+(lane_c&31), k = s*16+((lane_c>>5)&1)*8+j
    #pragma unroll
    for (int i=0;i<18;i++){
        int c = tid + i*512;
        int lane_c = c & 63, st = c >> 6;
        int s = st/6, t2 = st%6;
        int n = t2*32 + (lane_c&31), kb = s*16 + ((lane_c>>5)&1)*8;
        u32x4 vu;
        #pragma unroll
        for (int p=0;p<4;p++)
            vu[p] = pk2bf(W2[(kb+2*p)*192 + n], W2[(kb+2*p+1)*192 + n]);
        *(bf16x8*)(lw + c*8) = __builtin_bit_cast(bf16x8, vu);
    }
    __syncthreads();                                 // only barrier in the kernel

    const int lane = tid & 63, w = tid >> 6;
    const int m = lane & 31, q2 = lane >> 5;
    const int kbase = q2*8;
    const float b3v = b3[0];
    const float* w1c = W1 + 768*384;
    const float* w1d = W1 + 769*384;

    // layer-3 constants for this lane (n = t*32 + m), hoisted out of the t4 loop
    float b2r[6], w3r[6];
    #pragma unroll
    for (int t=0;t<6;t++){ b2r[t] = b2[t*32 + m]; w3r[t] = W3[t*32 + m]; }

    #pragma unroll 1
    for (int t4=0; t4<2; t4++){
        const int dcol = blockIdx.x*16 + t4*8 + w;   // doc column, < 4096
        const float dsv = dense_in[m*4096 + dcol];
        const float ssv = sparse[m*4096 + dcol];

        f32x16 acc[6];
        #pragma unroll
        for (int t=0;t<6;t++)
            #pragma unroll
            for (int r=0;r<16;r++) acc[t][r] = 0.0f;

        // 1-deep global prefetch
        f32x4 a0_c = *(const f32x4*)(Aq + m*384 + kbase);
        f32x4 a1_c = *(const f32x4*)(Aq + m*384 + kbase + 4);
        f32x4 b0_c = *(const f32x4*)(Bws + dcol*384 + kbase);
        f32x4 b1_c = *(const f32x4*)(Bws + dcol*384 + kbase + 4);

        #pragma unroll 1
        for (int s=0;s<24;s++){
            const int k0 = s*16 + kbase;
            const int kn = (s < 23) ? (k0 + 16) : kbase;     // dummy wrap on last iter
            const f32x4 a0_n = *(const f32x4*)(Aq + m*384 + kn);
            const f32x4 a1_n = *(const f32x4*)(Aq + m*384 + kn + 4);
            const f32x4 b0_n = *(const f32x4*)(Bws + dcol*384 + kn);
            const f32x4 b1_n = *(const f32x4*)(Bws + dcol*384 + kn + 4);
            const f32x4 wc0 = *(const f32x4*)(w1c + k0);
            const f32x4 wc1 = *(const f32x4*)(w1c + k0 + 4);
            const f32x4 wd0 = *(const f32x4*)(w1d + k0);
            const f32x4 wd1 = *(const f32x4*)(w1d + k0 + 4);
            f32x4 h0, h1;
            #pragma unroll
            for (int j=0;j<4;j++){
                h0[j] = fmaxf(a0_c[j] + b0_c[j] + dsv*wc0[j] + ssv*wd0[j], 0.0f);
                h1[j] = fmaxf(a1_c[j] + b1_c[j] + dsv*wc1[j] + ssv*wd1[j], 0.0f);
            }
            const bf16x8 fr = pk8(h0, h1);
            #pragma unroll
            for (int t=0;t<6;t++){
                const bf16x8 bfr = *(const bf16x8*)(lw + ((s*6 + t)*64 + lane)*8);
                acc[t] = __builtin_amdgcn_mfma_f32_32x32x16_bf16(fr, bfr, acc[t], 0, 0, 0);
            }
            a0_c = a0_n; a1_c = a1_n; b0_c = b0_n; b1_c = b1_n;
        }

        // layer 3: lane covers n = t*32+m
        float p[16];
        #pragma unroll
        for (int r=0;r<16;r++) p[r] = 0.0f;
        #pragma unroll
        for (int t=0;t<6;t++){
            #pragma unroll
            for (int r=0;r<16;r++)
                p[r] += fmaxf(acc[t][r] + b2r[t], 0.0f) * w3r[t];
        }
        #pragma unroll
        for (int mask=1; mask<32; mask<<=1){
            #pragma unroll
            for (int r=0;r<16;r++) p[r] += __shfl_xor(p[r], mask);
        }
        float myp = p[0];
        #pragma unroll
        for (int r=1;r<16;r++) myp = (m==r) ? p[r] : myp;
        if (m < 16){
            const int row = (m&3) + 8*(m>>2) + 4*q2;
            float logit = myp + b3v;
            float wgt = 1.0f/(1.0f + __expf(-logit));
            float dd = dense_in[row*4096 + dcol];
            float ss = sparse[row*4096 + dcol];
            out_final[row*4096 + dcol] = wgt*dd + (1.0f - wgt)*ss;
        }
    }
}

// ---------------------------------------------------------------- launch
extern "C" void kernel_launch(void* const* d_in, const int* in_sizes, int n_in,
                              void* d_out, int out_size, void* d_ws, size_t ws_size,
                              hipStream_t stream){
    const float* query  = (const float*)d_in[0];
    const float* doc    = (const float*)d_in[1];
    const float* sparse = (const float*)d_in[2];
    const float* W1     = (const float*)d_in[3];
    const float* b1     = (const float*)d_in[4];
    const float* W2     = (const float*)d_in[5];
    const float* b2     = (const float*)d_in[6];
    const float* W3     = (const float*)d_in[7];
    const float* b3     = (const float*)d_in[8];

    float* out_final  = (float*)d_out;                 // [32,4096]
    float* out_dense  = (float*)d_out + 131072;        // [32,4096]
    float* out_sparse = (float*)d_out + 262144;        // [32,4096]

    // workspace layout (16B-aligned), total 6,340,608 B
    float* Bws = (float*)d_ws;                                    // 6,291,456 B  (f32 [4096][384])
    float* Aq  = (float*)((char*)d_ws + 6291456);                 //    49,152 B  (f32 [32][384])

    hipLaunchKernelGGL(pre_kernel,  dim3(354), dim3(256), 0, stream,
                       query, doc, sparse, W1, b1, out_dense, out_sparse, Bws, Aq);
    hipLaunchKernelGGL(main_kernel, dim3(256), dim3(512), 0, stream,
                       Aq, Bws, W1, b2, W3, b3, sparse, W2, out_dense, out_final);
}